// Round 4
// baseline (92.873 us; speedup 1.0000x reference)
//
#include <hip/hip_runtime.h>
#include <stdint.h>

// Problem constants (match reference setup_inputs)
namespace {
constexpr int B = 4, P = 4, V = 4096, M = 2048;
constexpr int BP = B * P;
constexpr float BIGF = 1e10f;
constexpr int TPB   = 256;          // 4 waves per chamfer block (v1-proven)
constexpr int OTILE = 128;          // outer points per block (2 per lane)
constexpr int XT = V / OTILE;       // 32 x-role outer tiles
constexpr int YT = M / OTILE;       // 16 y-role outer tiles
constexpr int ROLES = XT + YT;      // 48 roles per bp
constexpr int CH = 512;             // inner elems staged per wave-chunk (8 KiB)
constexpr int KPB = 16;             // prep blocks per (b,p)
constexpr int VPB = V / KPB;        // 256 vertices per prep block
constexpr int MPB = M / KPB;        // 128 edgemap elems per prep block
}

typedef float f32x2 __attribute__((ext_vector_type(2)));

// workspace offsets (bytes)
//   0    nvalid (16 int)
//   64   sx     (16 float)
//   128  sy     (16 float)
//   192  done   (16 int)   per-bp role counters (hierarchical finalize)
//   256  done2  (1 int)    bp-level counter
//   512  pnk (BP*V float4) packed (x, y, |p|^2, 0) compacted projected pts
//   then epk (BP*M float4) packed (x, y, |e|^2, 0) edge points

// ---------------------------------------------------------------------------
// prep: 16 blocks per (b,p). Each block detects the mask layout, popcounts
// the mask prefix of earlier chunks to get its deterministic compaction base
// (no cross-block atomics), projects+compacts its 256 vertices, packs its
// 128 edgemap elems with norms. Last chunk-block writes nvalid; chunk-0
// blocks zero accumulators + per-bp done counter.  grid = BP*KPB = 256.
// ---------------------------------------------------------------------------
__global__ __launch_bounds__(256) void prep_kernel(
    const float* __restrict__ vertices,    // (B,V,3)
    const float* __restrict__ projmats,    // (P,3,4)
    const uint8_t* __restrict__ maskraw,   // (B,P,V) unknown elem layout
    const float* __restrict__ edgemaps,    // (B,P,M,2)
    int* __restrict__ nvalid,
    float* __restrict__ sx,
    float* __restrict__ sy,
    int* __restrict__ done,
    int* __restrict__ done2,
    float4* __restrict__ pnk,              // (BP,V)
    float4* __restrict__ epk)              // (BP,M)
{
    const int bp = blockIdx.x / KPB;
    const int k  = blockIdx.x % KPB;
    const int b = bp / P, p = bp % P;
    const int tid = threadIdx.x;
    const int lane = tid & 63;
    const int wave = tid >> 6;

    __shared__ int s_res[4];
    __shared__ int s_cnt;
    __shared__ int s_prew[4];
    if (tid < 4) { s_res[tid] = 0; s_prew[tid] = 0; }
    if (tid == 0) s_cnt = 0;
    __syncthreads();

    // --- detect mask element layout by byte-residue pattern (mod 4) ---
    // uint8 bernoulli(0.3): nonzero bytes at every residue.
    // int32 0/1 (LE):       nonzero only at residue 0.
    // float32 0/1.0f (LE):  nonzero only at residues 2 (0x80) and 3 (0x3f).
    uint32_t loc[4] = {0u, 0u, 0u, 0u};
    const int NB = 16384;   // 16 KiB prefix: >=4096 elems under every layout
    for (int i = tid * 16; i < NB; i += 256 * 16) {
        const uint32_t* w = (const uint32_t*)(maskraw + i);
        const uint32_t orw = w[0] | w[1] | w[2] | w[3];
        loc[0] |= orw & 0x000000FFu;
        loc[1] |= orw & 0x0000FF00u;
        loc[2] |= orw & 0x00FF0000u;
        loc[3] |= orw & 0xFF000000u;
    }
    #pragma unroll
    for (int j = 0; j < 4; ++j)
        if (loc[j]) atomicOr(&s_res[j], 1);
    __syncthreads();
    int layout;  // 0 = uint8/bool, 1 = int32, 2 = float32
    if (!s_res[1] && !s_res[2] && !s_res[3]) layout = 1;
    else if (!s_res[0] && !s_res[1])         layout = 2;
    else                                      layout = 0;

    // --- pack my edgemap slice with norms ---
    {
        const float2* eg = (const float2*)edgemaps + (size_t)bp * M;
        for (int m = k * MPB + tid; m < (k + 1) * MPB; m += 256) {
            const float2 e = eg[m];
            epk[(size_t)bp * M + m] =
                make_float4(e.x, e.y, fmaf(e.x, e.x, e.y * e.y), 0.f);
        }
    }

    // --- popcount mask prefix [0, k*VPB) -> deterministic compaction base ---
    const int pre_n = k * VPB;
    int cnt = 0;
    if (layout == 0) {
        const uint8_t* mk = maskraw + (size_t)bp * V;
        for (int i = tid; i < pre_n; i += 256) cnt += (mk[i] != 0);
    } else if (layout == 1) {
        const int* mk = (const int*)maskraw + (size_t)bp * V;
        for (int i = tid; i < pre_n; i += 256) cnt += (mk[i] != 0);
    } else {
        const float* mk = (const float*)maskraw + (size_t)bp * V;
        for (int i = tid; i < pre_n; i += 256) cnt += (mk[i] != 0.0f);
    }
    #pragma unroll
    for (int off = 32; off > 0; off >>= 1) cnt += __shfl_down(cnt, off, 64);
    if (lane == 0) s_prew[wave] = cnt;
    __syncthreads();
    const int pre_total = s_prew[0] + s_prew[1] + s_prew[2] + s_prew[3];

    // --- projection matrix for this view (uniform per block) ---
    float mm[12];
    #pragma unroll
    for (int j = 0; j < 12; ++j) mm[j] = projmats[p * 12 + j];

    // --- project + compact my 256 vertices (ballot-prefix compaction) ---
    for (int v = k * VPB + tid; v < (k + 1) * VPB; v += 256) {
        const int mi = bp * V + v;
        bool msk;
        if (layout == 0)      msk = maskraw[mi] != 0;
        else if (layout == 1) msk = ((const int*)maskraw)[mi] != 0;
        else                  msk = ((const float*)maskraw)[mi] != 0.0f;

        const unsigned long long ball = __ballot(msk);
        const int bcnt = __popcll(ball);
        int base = 0;
        if (lane == 0 && bcnt) base = atomicAdd(&s_cnt, bcnt);
        base = __shfl(base, 0, 64);
        if (msk) {
            const float x = vertices[(b * V + v) * 3 + 0];
            const float y = vertices[(b * V + v) * 3 + 1];
            const float z = vertices[(b * V + v) * 3 + 2];
            const float u  = mm[0]*x + mm[1]*y + mm[2]*z  + mm[3];
            const float vv = mm[4]*x + mm[5]*y + mm[6]*z  + mm[7];
            const float w  = mm[8]*x + mm[9]*y + mm[10]*z + mm[11];
            const int off = __popcll(ball & ((1ull << lane) - 1ull));
            const float rw = 1.0f / w;
            const float px = u * rw, py = vv * rw;
            pnk[(size_t)bp * V + pre_total + base + off] =
                make_float4(px, py, fmaf(px, px, py * py), 0.f);
        }
    }
    __syncthreads();
    if (tid == 0) {
        if (k == KPB - 1) nvalid[bp] = pre_total + s_cnt;
        if (k == 0) { sx[bp] = 0.0f; sy[bp] = 0.0f; done[bp] = 0; }
        if (blockIdx.x == 0) *done2 = 0;
    }
}

// ---------------------------------------------------------------------------
// chamfer: v1-proven structure (128 outers/block, 4 waves split inner range,
// wave-private LDS staging, no barriers in hot loop), with the hot loop
// VALU-packed:
//   v_pk_fma_f32 computes BOTH outer-chains per instruction using
//   op_sel/op_sel_hi broadcasts of (t.x|t.y|t.z) from the naturally-adjacent
//   register pairs of the staged float4 — zero broadcast movs:
//     r = pk_fma(t.y.bcast, (b0,b1), t.z.bcast)   op_sel:[1,0,0] hi:[1,1,0]
//     r = pk_fma(t.x.bcast, (a0,a1), r)           op_sel:[0,0,0] hi:[0,1,1]
//   mins fused over 2-elem steps -> v_min3_f32.
//   6 insts / 2 elems vs 12 before; bit-identical IEEE fma/min arithmetic.
// grid = (BP, ROLES), 256 threads; y-roles first; hierarchical done.
// ---------------------------------------------------------------------------
__global__ __launch_bounds__(TPB) void chamfer_kernel(
    const int* __restrict__ elen,          // (B,P)
    int* __restrict__ nvalid,
    float* __restrict__ sx,
    float* __restrict__ sy,
    int* __restrict__ done,
    int* __restrict__ done2,
    const float4* __restrict__ pnk,        // (BP,V)
    const float4* __restrict__ epk,        // (BP,M)
    float* __restrict__ out)               // (B)
{
    const int bp   = blockIdx.x;
    const int role = blockIdx.y;
    const int tid  = threadIdx.x;
    const int wave = tid >> 6;
    const int lane = tid & 63;
    const int len  = elen[bp];
    const int nv   = nvalid[bp];

    __shared__ float4 sb[4][CH];       // 32 KiB wave-private staging
    __shared__ float  smin[4][OTILE];  // 2 KiB merge buffer
    __shared__ int    s_last;

    const float4* outer; const float4* inner;
    int lim, L, obase;
    float* acc;
    const bool isY = (role < YT);      // y-roles dispatched first
    if (isY) {
        obase = role * OTILE;
        outer = epk + (size_t)bp * M;  lim = len;
        inner = pnk + (size_t)bp * V;  L = nv;
        acc = &sy[bp];
    } else {
        obase = (role - YT) * OTILE;
        outer = pnk + (size_t)bp * V;  lim = nv;
        inner = epk + (size_t)bp * M;  L = len;
        acc = &sx[bp];
    }
    const bool active = (obase < lim);   // block-uniform

    float pn0 = 0.f, pn1 = 0.f;
    if (active) {
        // my 2 outer points (same set for all 4 waves)
        const float4 p0 = outer[obase + lane];
        const float4 p1 = outer[obase + 64 + lane];
        const float a0 = -2.0f * p0.x, b0 = -2.0f * p0.y;  pn0 = p0.z;
        const float a1 = -2.0f * p1.x, b1 = -2.0f * p1.y;  pn1 = p1.z;
        const f32x2 apair = {a0, a1};
        const f32x2 bpair = {b0, b1};

        // wave-private inner range [s,e)
        const int q = (L + 3) >> 2;
        const int is = wave * q;
        const int ie = min(is + q, L);
        float4* sbw = sb[wave];

        float mn0 = BIGF, mn1 = BIGF;
        for (int cs = is; cs < ie; cs += CH) {
            const int cnt  = min(CH, ie - cs);
            const int cnt8 = (cnt + 7) & ~7;
            for (int j = lane; j < cnt; j += 64) sbw[j] = inner[cs + j];
            for (int j = cnt + lane; j < cnt8; j += 64)
                sbw[j] = make_float4(0.f, 0.f, BIGF, 0.f);   // exact no-op pad
            // wave-local RAW: compiler inserts lgkmcnt waits, no barrier
            const f32x2* sb2 = (const f32x2*)sbw;   // (t.x,t.y),(t.z,t.w) pairs
            #pragma unroll 4
            for (int j = 0; j < cnt8; j += 2) {
                const f32x2 txy0 = sb2[2 * j + 0], tzw0 = sb2[2 * j + 1];
                const f32x2 txy1 = sb2[2 * j + 2], tzw1 = sb2[2 * j + 3];
                f32x2 r0, r1;
                asm("v_pk_fma_f32 %0, %1, %2, %3 op_sel:[1,0,0] op_sel_hi:[1,1,0]"
                    : "=v"(r0) : "v"(txy0), "v"(bpair), "v"(tzw0));
                asm("v_pk_fma_f32 %0, %1, %2, %0 op_sel:[0,0,0] op_sel_hi:[0,1,1]"
                    : "+v"(r0) : "v"(txy0), "v"(apair));
                asm("v_pk_fma_f32 %0, %1, %2, %3 op_sel:[1,0,0] op_sel_hi:[1,1,0]"
                    : "=v"(r1) : "v"(txy1), "v"(bpair), "v"(tzw1));
                asm("v_pk_fma_f32 %0, %1, %2, %0 op_sel:[0,0,0] op_sel_hi:[0,1,1]"
                    : "+v"(r1) : "v"(txy1), "v"(apair));
                mn0 = fminf(fminf(r0.x, r1.x), mn0);   // -> v_min3_f32
                mn1 = fminf(fminf(r0.y, r1.y), mn1);
            }
        }
        smin[wave][lane]      = mn0;
        smin[wave][64 + lane] = mn1;
    }
    __syncthreads();                       // 'active' is block-uniform
    if (active && wave == 0) {
        const float m0 = fminf(fminf(smin[0][lane],      smin[1][lane]),
                               fminf(smin[2][lane],      smin[3][lane]));
        const float m1 = fminf(fminf(smin[0][64 + lane], smin[1][64 + lane]),
                               fminf(smin[2][64 + lane], smin[3][64 + lane]));
        float val = 0.0f;
        if (obase + lane < lim)      val += fmaxf(m0 + pn0, 0.0f);
        if (obase + 64 + lane < lim) val += fmaxf(m1 + pn1, 0.0f);
        #pragma unroll
        for (int off = 32; off > 0; off >>= 1)
            val += __shfl_down(val, off, 64);
        if (lane == 0) atomicAdd(acc, val);
    }

    // hierarchical done: ROLES blocks per bp -> done[bp]; 16 bp -> done2.
    __syncthreads();
    if (tid == 0) {
        __threadfence();                               // release our adds
        int lastall = 0;
        const int old = atomicAdd(&done[bp], 1);
        if (old == ROLES - 1) {
            __threadfence();
            const int o2 = atomicAdd(done2, 1);
            lastall = (o2 == BP - 1) ? 1 : 0;
        }
        s_last = lastall;
    }
    __syncthreads();
    if (s_last) {
        __threadfence();                               // acquire others' adds
        if (tid < B) {
            float o = 0.0f;
            #pragma unroll
            for (int p = 0; p < P; ++p) {
                const int j = tid * P + p;
                o += sx[j] / fmaxf((float)nvalid[j], 1.0f)
                   + sy[j] / fmaxf((float)elen[j], 1.0f);
            }
            out[tid] = o * (1.0f / P);
        }
    }
}

extern "C" void kernel_launch(void* const* d_in, const int* in_sizes, int n_in,
                              void* d_out, int out_size, void* d_ws, size_t ws_size,
                              hipStream_t stream)
{
    const float*   vertices = (const float*)d_in[0];
    const float*   projmats = (const float*)d_in[1];
    const float*   edgemaps = (const float*)d_in[2];
    const uint8_t* maskraw  = (const uint8_t*)d_in[3];
    const int*     elen     = (const int*)d_in[4];
    float* out = (float*)d_out;

    char* ws = (char*)d_ws;
    int*    nvalid = (int*)(ws + 0);
    float*  sx     = (float*)(ws + 64);
    float*  sy     = (float*)(ws + 128);
    int*    done   = (int*)(ws + 192);
    int*    done2  = (int*)(ws + 256);
    float4* pnk    = (float4*)(ws + 512);
    float4* epk    = pnk + (size_t)BP * V;

    prep_kernel<<<BP * KPB, 256, 0, stream>>>(vertices, projmats, maskraw,
                                              edgemaps, nvalid, sx, sy, done,
                                              done2, pnk, epk);
    chamfer_kernel<<<dim3(BP, ROLES), TPB, 0, stream>>>(elen, nvalid, sx, sy,
                                                        done, done2, pnk, epk,
                                                        out);
}